// Round 5
// baseline (10746.762 us; speedup 1.0000x reference)
//
#include <hip/hip_runtime.h>
#include <stdint.h>

#define H 256
#define BB 64
#define TT 2048
#define G4 1024
#define LDX 264   // padded LDS row stride (elems): 528 B, 16B-aligned, balanced banks

typedef __attribute__((ext_vector_type(8))) short short8;
typedef __attribute__((ext_vector_type(4))) float float4_;
typedef unsigned long long ull;
typedef unsigned short ushort_t;
typedef unsigned int uint_t;
typedef __attribute__((ext_vector_type(4))) uint_t uint4_;

static __device__ __forceinline__ float bfhi2f(ushort_t u) {
    union { unsigned int i; float f; } v; v.i = ((unsigned int)u) << 16; return v.f;
}
static __device__ __forceinline__ ushort_t f2bf(float x) {
    union { float f; unsigned int i; } v; v.f = x;
    unsigned int u = v.i;
    return (ushort_t)((u + 0x7FFFu + ((u >> 16) & 1u)) >> 16);
}
static __device__ __forceinline__ void split2(float x, ushort_t& hi, ushort_t& lo) {
    hi = f2bf(x);
    lo = f2bf(x - bfhi2f(hi));
}
static __device__ __forceinline__ float sigm(float x) { return 1.0f / (1.0f + __expf(-x)); }
static __device__ __forceinline__ float tanh_(float x) { return 2.0f / (1.0f + __expf(-2.0f * x)) - 1.0f; }

// ---- split fp32 weights into transposed bf16 hi/lo planes: planes[mat][plane][g][k] ----
__global__ __launch_bounds__(256) void split_w(const float* __restrict__ Wx,
                                               const float* __restrict__ Wh,
                                               ushort_t* __restrict__ planes) {
    const int g = blockIdx.x & 1023;
    const int mat = blockIdx.x >> 10;
    const int k = threadIdx.x;
    const float* src = mat ? Wh : Wx;
    float v = src[(size_t)k * G4 + g];
    ushort_t hi, lo; split2(v, hi, lo);
    ushort_t* ph = planes + (size_t)mat * 2 * G4 * 256;
    ph[g * 256 + k] = hi;
    ph[(size_t)G4 * 256 + g * 256 + k] = lo;
}

// ---- fused LSTM scan, split-bf16 (fp32-grade) arithmetic ----
// grid = 512. Workers: blocks with (b&7)<4 and (b>>3)<16 -> grp=b&7, s=b>>3.
// Under the CP's round-robin block->XCD mapping (XCD = b&7), ALL 16 blocks of
// group g land on XCD g => the h exchange stays inside one XCD's L2:
//   publish = plain (write-through) store to fast lines + agent store to mirror;
//   poll    = sc0-only loads (bypass L1, hit own-XCD L2, ~250 cy RT).
// If the mapping assumption is wrong, polling times out ONCE (sticky) and falls
// back to the mirror/agent path == round-1 proven behavior. Remaining 448 blocks
// are clock ballast (round-4 proven, +7%).
__global__ __launch_bounds__(256, 1) void lstm_scan(
        const float* __restrict__ x,    // [B][T][256]
        const float* __restrict__ bx,   // [1024]
        const float* __restrict__ bh,   // [1024]
        const ushort_t* __restrict__ WxTh, const ushort_t* __restrict__ WxTl,
        const ushort_t* __restrict__ WhTh, const ushort_t* __restrict__ WhTl,
        float* __restrict__ out0,       // [B][T][256]
        float* __restrict__ outh,       // [B][256]
        float* __restrict__ outc,       // [B][256]
        uint_t* __restrict__ hbuf,      // fast: [2 par][4 grp][16 batch][256 col] fp32+tag
        uint_t* __restrict__ mbuf,      // mirror (agent scope), same layout
        uint_t* __restrict__ ctrl) {    // [0] = worker-done counter
    __shared__ ushort_t xah[16 * LDX], xal[16 * LDX];
    __shared__ ushort_t hsh[16 * LDX], hsl[16 * LDX];
    __shared__ float gatesL[1024];
    __shared__ float cst[256];
    __shared__ float bL[64];

    const int tid = threadIdx.x;
    const int b = blockIdx.x;
    const int isWorker = ((b & 7) < 4) && ((b >> 3) < 16);

    if (!isWorker) {
        // ================= ballast: keep the clock governor awake =================
        __shared__ int bdone;
        if (tid == 0) bdone = 0;
        __syncthreads();
        float a0 = 1.0f + tid * 1e-7f, a1 = 1.1f, a2 = 1.2f, a3 = 1.3f;
        const float bm = 1.0000001f, cm = 1e-9f;
        for (int it = 0; it < 40000; ++it) {
#pragma unroll 32
            for (int k = 0; k < 256; ++k) {
                a0 = __builtin_fmaf(a0, bm, cm);
                a1 = __builtin_fmaf(a1, bm, cm);
                a2 = __builtin_fmaf(a2, bm, cm);
                a3 = __builtin_fmaf(a3, bm, cm);
            }
            if (tid == 0 &&
                __hip_atomic_load(&ctrl[0], __ATOMIC_RELAXED, __HIP_MEMORY_SCOPE_AGENT) >= 64u)
                bdone = 1;
            __syncthreads();
            if (bdone) break;
        }
        asm volatile("" :: "v"(a0), "v"(a1), "v"(a2), "v"(a3));   // keep live (no DCE)
        return;
    }

    // ============================ worker (round-4 core) ===========================
    const int grp = b & 7;          // 0..3
    const int s = b >> 3;           // 0..15
    const int lane = tid & 63, wave = tid >> 6;
    const int lm = lane & 15, lq = lane >> 4;
    const int pb = tid >> 4, pj = tid & 15;

    if (tid < 64) {
        int g = ((tid >> 4) << 8) + (s << 4) + (tid & 15);
        bL[tid] = bx[g] + bh[g];
    }
    cst[tid] = 0.0f;

    // loop-invariant B-fragments (our 16 gate cols of Wx and Wh, hi+lo) in registers
    const size_t wrow = ((size_t)((wave << 8) + (s << 4) + lm)) * 256;
    short8 fxh[8], fxl[8], fhh[8], fhl[8];
#pragma unroll
    for (int kc = 0; kc < 8; ++kc) {
        fxh[kc] = *(const short8*)(WxTh + wrow + kc * 32 + lq * 8);
        fxl[kc] = *(const short8*)(WxTl + wrow + kc * 32 + lq * 8);
        fhh[kc] = *(const short8*)(WhTh + wrow + kc * 32 + lq * 8);
        fhl[kc] = *(const short8*)(WhTl + wrow + kc * 32 + lq * 8);
    }

    const float* xp0 = x + ((size_t)(grp * 16 + pb)) * TT * 256 + pj * 16;
    float* o0 = out0 + ((size_t)(grp * 16 + pb)) * TT * H + (s << 4) + pj;

    // prefetch x_0 into registers
    float4_ xv[4];
#pragma unroll
    for (int q = 0; q < 4; ++q) xv[q] = *(const float4_*)(xp0 + q * 4);

    const int rb = pb * LDX + pj * 16;
    int fastpoll = 1;               // sticky: drops to 0 if fast lines ever time out

    for (int t = 0; t < TT; ++t) {
        // ---- stage prefetched x_t: split to hi/lo LDS ----
#pragma unroll
        for (int q = 0; q < 4; ++q) {
            union { ushort_t u[4]; ull q8; } ph_, pl_;
#pragma unroll
            for (int e = 0; e < 4; ++e) {
                ushort_t hi, lo; split2(xv[q][e], hi, lo);
                ph_.u[e] = hi; pl_.u[e] = lo;
            }
            *(ull*)(xah + rb + q * 4) = ph_.q8;
            *(ull*)(xal + rb + q * 4) = pl_.q8;
        }
        __syncthreads();   // S1: xa visible

        // ---- x @ Wx (independent of h; overlaps publish-propagation of writers) ----
        float4_ acc = {};
#pragma unroll
        for (int kc = 0; kc < 8; ++kc) {
            short8 ah = *(const short8*)(xah + lm * LDX + kc * 32 + lq * 8);
            short8 al = *(const short8*)(xal + lm * LDX + kc * 32 + lq * 8);
            acc = __builtin_amdgcn_mfma_f32_16x16x32_bf16(ah, fxh[kc], acc, 0, 0, 0);
            acc = __builtin_amdgcn_mfma_f32_16x16x32_bf16(ah, fxl[kc], acc, 0, 0, 0);
            acc = __builtin_amdgcn_mfma_f32_16x16x32_bf16(al, fxh[kc], acc, 0, 0, 0);
        }

        uint_t w[16];
        if (t > 0) {
            // ---- poll own 64B line (batch pb, cols pj*16..+15, writer block s'=pj) ----
            const size_t ridx = ((size_t)((((t & 1) << 2) + grp) << 12)) + (pb << 8) + (pj << 4);
            const uint_t* hp = hbuf + ridx;
            const uint_t* mp = mbuf + ridx;
            const uint_t texp = (uint_t)(t & 127);
            int got = 0;
            if (fastpoll) {
                const int limit = (t == 1) ? 16384 : 512;   // t=1: prologue skew allowance
                int rounds = 0;
                while (rounds < limit) {
                    uint4_ a0, a1, a2, a3;
                    asm volatile(
                        "global_load_dwordx4 %0, %4, off sc0\n\t"
                        "global_load_dwordx4 %1, %4, off offset:16 sc0\n\t"
                        "global_load_dwordx4 %2, %4, off offset:32 sc0\n\t"
                        "global_load_dwordx4 %3, %4, off offset:48 sc0\n\t"
                        "s_waitcnt vmcnt(0)"
                        : "=&v"(a0), "=&v"(a1), "=&v"(a2), "=&v"(a3)
                        : "v"(hp) : "memory");
                    bool ok = true;
#pragma unroll
                    for (int e = 0; e < 4; ++e) {
                        ok &= ((a0[e] & 127u) == texp); ok &= ((a1[e] & 127u) == texp);
                        ok &= ((a2[e] & 127u) == texp); ok &= ((a3[e] & 127u) == texp);
                    }
                    if (ok) {
#pragma unroll
                        for (int e = 0; e < 4; ++e) {
                            w[e] = a0[e]; w[4 + e] = a1[e]; w[8 + e] = a2[e]; w[12 + e] = a3[e];
                        }
                        got = 1; break;
                    }
                    ++rounds;
                }
                if (!got) fastpoll = 0;   // sticky fallback: mapping assumption failed
            }
            if (!got) {
                while (true) {
                    bool ok = true;
#pragma unroll
                    for (int e = 0; e < 16; ++e)
                        w[e] = __hip_atomic_load(mp + e, __ATOMIC_RELAXED, __HIP_MEMORY_SCOPE_AGENT);
#pragma unroll
                    for (int e = 0; e < 16; ++e) ok &= ((w[e] & 127u) == texp);
                    if (ok) break;
                }
            }
        }

        // ---- prefetch x_{t+1} AFTER the poll: its HBM latency hides under the
        //      h-stage + S2 + h-MFMA stretch instead of being drained by the poll ----
        if (t + 1 < TT) {
            const float* xp = xp0 + (size_t)(t + 1) * 256;
#pragma unroll
            for (int q = 0; q < 4; ++q) xv[q] = *(const float4_*)(xp + q * 4);
        }

        if (t > 0) {
            // ---- split (deterministic, identical on all blocks) and stage into LDS ----
#pragma unroll
            for (int q = 0; q < 4; ++q) {
                union { ushort_t u[4]; ull q8; } ph_, pl_;
#pragma unroll
                for (int e = 0; e < 4; ++e) {
                    float v = __uint_as_float(w[q * 4 + e] & ~127u);
                    ushort_t hi, lo; split2(v, hi, lo);
                    ph_.u[e] = hi; pl_.u[e] = lo;
                }
                *(ull*)(hsh + rb + q * 4) = ph_.q8;
                *(ull*)(hsl + rb + q * 4) = pl_.q8;
            }
            __syncthreads();   // S2: h planes visible

            // ---- h @ Wh ----
#pragma unroll
            for (int kc = 0; kc < 8; ++kc) {
                short8 ah = *(const short8*)(hsh + lm * LDX + kc * 32 + lq * 8);
                short8 al = *(const short8*)(hsl + lm * LDX + kc * 32 + lq * 8);
                acc = __builtin_amdgcn_mfma_f32_16x16x32_bf16(ah, fhh[kc], acc, 0, 0, 0);
                acc = __builtin_amdgcn_mfma_f32_16x16x32_bf16(ah, fhl[kc], acc, 0, 0, 0);
                acc = __builtin_amdgcn_mfma_f32_16x16x32_bf16(al, fhh[kc], acc, 0, 0, 0);
            }
        }

        // C layout: col = lane&15 (=j), row = (lane>>4)*4+r (=batch)
#pragma unroll
        for (int r = 0; r < 4; ++r)
            gatesL[(wave << 8) + ((lq * 4 + r) << 4) + lm] = acc[r];
        __syncthreads();   // S3: gates ready

        // ---- pointwise cell: thread = (batch pb, col pj) ----
        float g0 = gatesL[tid]       + bL[pj];        // f
        float g1 = gatesL[256 + tid] + bL[16 + pj];   // i
        float g2 = gatesL[512 + tid] + bL[32 + pj];   // o
        float g3 = gatesL[768 + tid] + bL[48 + pj];   // chat
        float ft = sigm(g0), it = sigm(g1), ot = sigm(g2), ch = tanh_(g3);
        float c = ft * cst[tid] + it * ch;
        cst[tid] = c;
        float hv = ot * tanh_(c);

        // mask low 7 mantissa bits (tag space); recurrence AND output use the masked value
        uint_t um = __float_as_uint(hv) & ~127u;
        float hm = __uint_as_float(um);
        o0[(size_t)t * H] = hm;

        // ---- publish tagged word: fast line (plain/write-through) + mirror (agent) ----
        const uint_t tagged = um | (uint_t)((t + 1) & 127);
        const size_t widx = ((size_t)(((((t & 1) ^ 1) << 2) + grp) << 12)) + (pb << 8) + (s << 4) + pj;
        __hip_atomic_store(hbuf + widx, tagged, __ATOMIC_RELAXED, __HIP_MEMORY_SCOPE_WORKGROUP);
        __hip_atomic_store(mbuf + widx, tagged, __ATOMIC_RELAXED, __HIP_MEMORY_SCOPE_AGENT);

        if (t == TT - 1) {
            outh[(grp * 16 + pb) * H + (s << 4) + pj] = hm;
            outc[(grp * 16 + pb) * H + (s << 4) + pj] = c;
        }
        // no trailing barrier: tag protocol is self-validating per 4B word
    }

    // signal ballast that this worker block is done
    if (tid == 0)
        __hip_atomic_fetch_add(&ctrl[0], 1u, __ATOMIC_RELEASE, __HIP_MEMORY_SCOPE_AGENT);
}

extern "C" void kernel_launch(void* const* d_in, const int* in_sizes, int n_in,
                              void* d_out, int out_size, void* d_ws, size_t ws_size,
                              hipStream_t stream) {
    (void)in_sizes; (void)n_in; (void)out_size; (void)ws_size;
    const float* x  = (const float*)d_in[0];
    const float* Wx = (const float*)d_in[1];
    const float* Wh = (const float*)d_in[2];
    const float* bx = (const float*)d_in[3];
    const float* bh = (const float*)d_in[4];
    float* out0 = (float*)d_out;
    float* outh = out0 + (size_t)BB * TT * H;
    float* outc = outh + (size_t)BB * H;

    // ws: hbuf 128K | mbuf 128K | ctrl 128 B | W planes 2 MB
    uint_t* hbuf = (uint_t*)d_ws;
    uint_t* mbuf = (uint_t*)((char*)d_ws + 131072);
    uint_t* ctrl = (uint_t*)((char*)d_ws + 262144);
    ushort_t* planes = (ushort_t*)((char*)d_ws + 262144 + 128);

    hipMemsetAsync(d_ws, 0, 262144 + 128, stream);
    split_w<<<2048, 256, 0, stream>>>(Wx, Wh, planes);
    lstm_scan<<<512, 256, 0, stream>>>(x, bx, bh,
        planes,
        planes + (size_t)G4 * 256,
        planes + (size_t)2 * G4 * 256,
        planes + (size_t)3 * G4 * 256,
        out0, outh, outc, hbuf, mbuf, ctrl);
}

// Round 6
// 7927.489 us; speedup vs baseline: 1.3556x; 1.3556x over previous
//
#include <hip/hip_runtime.h>
#include <stdint.h>

#define H 256
#define BB 64
#define TT 2048
#define G4 1024
#define LDX 264   // padded LDS row stride (elems): 528 B, 16B-aligned, balanced banks

typedef __attribute__((ext_vector_type(8))) short short8;
typedef __attribute__((ext_vector_type(4))) float float4_;
typedef unsigned long long ull;
typedef unsigned short ushort_t;
typedef unsigned int uint_t;
typedef __attribute__((ext_vector_type(4))) uint_t uint4_;

static __device__ __forceinline__ float bfhi2f(ushort_t u) {
    union { unsigned int i; float f; } v; v.i = ((unsigned int)u) << 16; return v.f;
}
static __device__ __forceinline__ ushort_t f2bf(float x) {
    union { float f; unsigned int i; } v; v.f = x;
    unsigned int u = v.i;
    return (ushort_t)((u + 0x7FFFu + ((u >> 16) & 1u)) >> 16);
}
static __device__ __forceinline__ void split2(float x, ushort_t& hi, ushort_t& lo) {
    hi = f2bf(x);
    lo = f2bf(x - bfhi2f(hi));
}
static __device__ __forceinline__ float sigm(float x) { return 1.0f / (1.0f + __expf(-x)); }
static __device__ __forceinline__ float tanh_(float x) { return 2.0f / (1.0f + __expf(-2.0f * x)) - 1.0f; }

// ---- split fp32 weights into transposed bf16 hi/lo planes: planes[mat][plane][g][k] ----
__global__ __launch_bounds__(256) void split_w(const float* __restrict__ Wx,
                                               const float* __restrict__ Wh,
                                               ushort_t* __restrict__ planes) {
    const int g = blockIdx.x & 1023;
    const int mat = blockIdx.x >> 10;
    const int k = threadIdx.x;
    const float* src = mat ? Wh : Wx;
    float v = src[(size_t)k * G4 + g];
    ushort_t hi, lo; split2(v, hi, lo);
    ushort_t* ph = planes + (size_t)mat * 2 * G4 * 256;
    ph[g * 256 + k] = hi;
    ph[(size_t)G4 * 256 + g * 256 + k] = lo;
}

// ---- fused LSTM scan, split-bf16 (fp32-grade) arithmetic ----
// grid = 256 (1 block/CU). Blocks 0..63: workers (round-4 proven core, tagged-word
// agent-scope exchange). Blocks 64..255: clock ballast.
//
// Round-6 changes (exchange-fabric decongestion):
//  * ballast: dense 8-accumulator FMA body; ctrl[0] checked ONLY by tid 0, ONLY every
//    8th outer iter (LDS-flag broadcast). Round 4 had 49k ballast threads each
//    agent-loading the same LLC line every ~2.7k cy (~18 same-line reqs/cy) — direct
//    contention on the fabric path the h-exchange uses.
//  * poll rounds: 4x global_load_dwordx4 sc0 sc1 (one 64B line, 4 instrs) instead of
//    16 separate atomic dword loads — shorter round (lower detect quantization),
//    4x less poll traffic. Pre-issue batch stays compiler-managed atomic loads
//    (safe in-flight register handling across the x-MFMA window).
//  * writer tail: publish the tagged word BEFORE out0/outh/outc stores.
__global__ __launch_bounds__(256, 1) void lstm_scan(
        const float* __restrict__ x,    // [B][T][256]
        const float* __restrict__ bx,   // [1024]
        const float* __restrict__ bh,   // [1024]
        const ushort_t* __restrict__ WxTh, const ushort_t* __restrict__ WxTl,
        const ushort_t* __restrict__ WhTh, const ushort_t* __restrict__ WhTl,
        float* __restrict__ out0,       // [B][T][256]
        float* __restrict__ outh,       // [B][256]
        float* __restrict__ outc,       // [B][256]
        uint_t* __restrict__ hbuf,      // [2 par][4 grp][16 batch][256 col] fp32+tag
        uint_t* __restrict__ ctrl) {    // [0] = worker-done counter
    __shared__ ushort_t xah[16 * LDX], xal[16 * LDX];
    __shared__ ushort_t hsh[16 * LDX], hsl[16 * LDX];
    __shared__ float gatesL[1024];
    __shared__ float cst[256];
    __shared__ float bL[64];

    const int tid = threadIdx.x;

    if (blockIdx.x >= 64) {
        // ========== ballast: keep clocks up WITHOUT hammering the LLC ==========
        __shared__ int bdone;
        if (tid == 0) bdone = 0;
        __syncthreads();
        float a0 = 1.0f + tid * 1e-7f, a1 = 1.1f, a2 = 1.2f, a3 = 1.3f;
        float a4 = 1.4f, a5 = 1.5f, a6 = 1.6f, a7 = 1.7f;
        const float bm = 1.0000001f, cm = 1e-9f;
        for (int outer = 0; outer < 20000; ++outer) {
#pragma unroll
            for (int k = 0; k < 128; ++k) {
                a0 = __builtin_fmaf(a0, bm, cm);
                a1 = __builtin_fmaf(a1, bm, cm);
                a2 = __builtin_fmaf(a2, bm, cm);
                a3 = __builtin_fmaf(a3, bm, cm);
                a4 = __builtin_fmaf(a4, bm, cm);
                a5 = __builtin_fmaf(a5, bm, cm);
                a6 = __builtin_fmaf(a6, bm, cm);
                a7 = __builtin_fmaf(a7, bm, cm);
            }
            if ((outer & 7) == 7) {
                if (tid == 0 &&
                    __hip_atomic_load(&ctrl[0], __ATOMIC_RELAXED, __HIP_MEMORY_SCOPE_AGENT) >= 64u)
                    bdone = 1;
                __syncthreads();
                if (bdone) break;
                __syncthreads();
            }
        }
        asm volatile("" :: "v"(a0), "v"(a1), "v"(a2), "v"(a3),
                           "v"(a4), "v"(a5), "v"(a6), "v"(a7));   // keep live (no DCE)
        return;
    }

    // ============================ worker (round-4 core) ===========================
    const int grp = blockIdx.x & 3;
    const int s = blockIdx.x >> 2;
    const int lane = tid & 63, wave = tid >> 6;
    const int lm = lane & 15, lq = lane >> 4;
    const int pb = tid >> 4, pj = tid & 15;

    if (tid < 64) {
        int g = ((tid >> 4) << 8) + (s << 4) + (tid & 15);
        bL[tid] = bx[g] + bh[g];
    }
    cst[tid] = 0.0f;

    // loop-invariant B-fragments (our 16 gate cols of Wx and Wh, hi+lo) in registers
    const size_t wrow = ((size_t)((wave << 8) + (s << 4) + lm)) * 256;
    short8 fxh[8], fxl[8], fhh[8], fhl[8];
#pragma unroll
    for (int kc = 0; kc < 8; ++kc) {
        fxh[kc] = *(const short8*)(WxTh + wrow + kc * 32 + lq * 8);
        fxl[kc] = *(const short8*)(WxTl + wrow + kc * 32 + lq * 8);
        fhh[kc] = *(const short8*)(WhTh + wrow + kc * 32 + lq * 8);
        fhl[kc] = *(const short8*)(WhTl + wrow + kc * 32 + lq * 8);
    }

    const float* xp0 = x + ((size_t)(grp * 16 + pb)) * TT * 256 + pj * 16;
    float* o0 = out0 + ((size_t)(grp * 16 + pb)) * TT * H + (s << 4) + pj;

    // prefetch x_0 into registers
    float4_ xv[4];
#pragma unroll
    for (int q = 0; q < 4; ++q) xv[q] = *(const float4_*)(xp0 + q * 4);

    const int rb = pb * LDX + pj * 16;

    for (int t = 0; t < TT; ++t) {
        // ---- stage prefetched x_t: split to hi/lo LDS ----
#pragma unroll
        for (int q = 0; q < 4; ++q) {
            union { ushort_t u[4]; ull q8; } ph_, pl_;
#pragma unroll
            for (int e = 0; e < 4; ++e) {
                ushort_t hi, lo; split2(xv[q][e], hi, lo);
                ph_.u[e] = hi; pl_.u[e] = lo;
            }
            *(ull*)(xah + rb + q * 4) = ph_.q8;
            *(ull*)(xal + rb + q * 4) = pl_.q8;
        }
        __syncthreads();   // S1: xa visible

        // ---- pre-issue first h poll batch (compiler-managed; in flight across x-MFMAs;
        //      thread (pb,pj) owns batch pb, cols pj*16..+15, writer block s'=pj) ----
        const uint_t* hp = hbuf + ((((t & 1) << 2) + grp) << 12) + (pb << 8) + (pj << 4);
        uint_t w[16];
        if (t > 0) {
#pragma unroll
            for (int e = 0; e < 16; ++e)
                w[e] = __hip_atomic_load(hp + e, __ATOMIC_RELAXED, __HIP_MEMORY_SCOPE_AGENT);
        }

        // ---- x @ Wx (independent of h; overlaps publish-propagation + poll latency) ----
        float4_ acc = {};
#pragma unroll
        for (int kc = 0; kc < 8; ++kc) {
            short8 ah = *(const short8*)(xah + lm * LDX + kc * 32 + lq * 8);
            short8 al = *(const short8*)(xal + lm * LDX + kc * 32 + lq * 8);
            acc = __builtin_amdgcn_mfma_f32_16x16x32_bf16(ah, fxh[kc], acc, 0, 0, 0);
            acc = __builtin_amdgcn_mfma_f32_16x16x32_bf16(ah, fxl[kc], acc, 0, 0, 0);
            acc = __builtin_amdgcn_mfma_f32_16x16x32_bf16(al, fxh[kc], acc, 0, 0, 0);
        }

        if (t > 0) {
            // ---- poll: 64B line via 4x dwordx4 sc0 sc1 per round; tags self-validate ----
            const uint_t texp = (uint_t)(t & 127);
            while (true) {
                bool ok = true;
#pragma unroll
                for (int e = 0; e < 16; ++e) ok &= ((w[e] & 127u) == texp);
                if (ok) break;
                uint4_ b0, b1, b2, b3;
                asm volatile(
                    "global_load_dwordx4 %0, %4, off sc0 sc1\n\t"
                    "global_load_dwordx4 %1, %4, off offset:16 sc0 sc1\n\t"
                    "global_load_dwordx4 %2, %4, off offset:32 sc0 sc1\n\t"
                    "global_load_dwordx4 %3, %4, off offset:48 sc0 sc1\n\t"
                    "s_waitcnt vmcnt(0)"
                    : "=&v"(b0), "=&v"(b1), "=&v"(b2), "=&v"(b3)
                    : "v"(hp) : "memory");
#pragma unroll
                for (int e = 0; e < 4; ++e) {
                    w[e] = b0[e]; w[4 + e] = b1[e]; w[8 + e] = b2[e]; w[12 + e] = b3[e];
                }
            }
        }

        // ---- prefetch x_{t+1} AFTER the poll: HBM latency hides under h-stage + S2 +
        //      h-MFMA instead of being drained by the poll's vmcnt(0) ----
        if (t + 1 < TT) {
            const float* xp = xp0 + (size_t)(t + 1) * 256;
#pragma unroll
            for (int q = 0; q < 4; ++q) xv[q] = *(const float4_*)(xp + q * 4);
        }

        if (t > 0) {
            // ---- split (deterministic, identical on all blocks) and stage into LDS ----
#pragma unroll
            for (int q = 0; q < 4; ++q) {
                union { ushort_t u[4]; ull q8; } ph_, pl_;
#pragma unroll
                for (int e = 0; e < 4; ++e) {
                    float v = __uint_as_float(w[q * 4 + e] & ~127u);
                    ushort_t hi, lo; split2(v, hi, lo);
                    ph_.u[e] = hi; pl_.u[e] = lo;
                }
                *(ull*)(hsh + rb + q * 4) = ph_.q8;
                *(ull*)(hsl + rb + q * 4) = pl_.q8;
            }
            __syncthreads();   // S2: h planes visible

            // ---- h @ Wh ----
#pragma unroll
            for (int kc = 0; kc < 8; ++kc) {
                short8 ah = *(const short8*)(hsh + lm * LDX + kc * 32 + lq * 8);
                short8 al = *(const short8*)(hsl + lm * LDX + kc * 32 + lq * 8);
                acc = __builtin_amdgcn_mfma_f32_16x16x32_bf16(ah, fhh[kc], acc, 0, 0, 0);
                acc = __builtin_amdgcn_mfma_f32_16x16x32_bf16(ah, fhl[kc], acc, 0, 0, 0);
                acc = __builtin_amdgcn_mfma_f32_16x16x32_bf16(al, fhh[kc], acc, 0, 0, 0);
            }
        }

        // C layout: col = lane&15 (=j), row = (lane>>4)*4+r (=batch)
#pragma unroll
        for (int r = 0; r < 4; ++r)
            gatesL[(wave << 8) + ((lq * 4 + r) << 4) + lm] = acc[r];
        __syncthreads();   // S3: gates ready

        // ---- pointwise cell: thread = (batch pb, col pj) ----
        float g0 = gatesL[tid]       + bL[pj];        // f
        float g1 = gatesL[256 + tid] + bL[16 + pj];   // i
        float g2 = gatesL[512 + tid] + bL[32 + pj];   // o
        float g3 = gatesL[768 + tid] + bL[48 + pj];   // chat
        float ft = sigm(g0), it = sigm(g1), ot = sigm(g2), ch = tanh_(g3);
        float c = ft * cst[tid] + it * ch;
        cst[tid] = c;
        float hv = ot * tanh_(c);

        // mask low 7 mantissa bits (tag space); recurrence AND output use the masked value
        uint_t um = __float_as_uint(hv) & ~127u;

        // ---- publish FIRST (shortest writer tail), then local output stores ----
        uint_t* hw = hbuf + (((((t & 1) ^ 1) << 2) + grp) << 12) + (pb << 8) + (s << 4) + pj;
        __hip_atomic_store(hw, um | (uint_t)((t + 1) & 127), __ATOMIC_RELAXED, __HIP_MEMORY_SCOPE_AGENT);

        float hm = __uint_as_float(um);
        o0[(size_t)t * H] = hm;
        if (t == TT - 1) {
            outh[(grp * 16 + pb) * H + (s << 4) + pj] = hm;
            outc[(grp * 16 + pb) * H + (s << 4) + pj] = c;
        }
        // no trailing barrier: tag protocol is self-validating per 4B word
    }

    // signal ballast that this worker block is done
    if (tid == 0)
        __hip_atomic_fetch_add(&ctrl[0], 1u, __ATOMIC_RELEASE, __HIP_MEMORY_SCOPE_AGENT);
}

extern "C" void kernel_launch(void* const* d_in, const int* in_sizes, int n_in,
                              void* d_out, int out_size, void* d_ws, size_t ws_size,
                              hipStream_t stream) {
    (void)in_sizes; (void)n_in; (void)out_size; (void)ws_size;
    const float* x  = (const float*)d_in[0];
    const float* Wx = (const float*)d_in[1];
    const float* Wh = (const float*)d_in[2];
    const float* bx = (const float*)d_in[3];
    const float* bh = (const float*)d_in[4];
    float* out0 = (float*)d_out;
    float* outh = out0 + (size_t)BB * TT * H;
    float* outc = outh + (size_t)BB * H;

    // ws layout: hbuf [2][4][16][256] fp32 = 131072 B | ctrl 128 B | W planes 2 MB
    uint_t* hbuf = (uint_t*)d_ws;
    uint_t* ctrl = (uint_t*)((char*)d_ws + 131072);
    ushort_t* planes = (ushort_t*)((char*)d_ws + 131072 + 128);

    hipMemsetAsync(d_ws, 0, 131072 + 128, stream);
    split_w<<<2048, 256, 0, stream>>>(Wx, Wh, planes);
    lstm_scan<<<256, 256, 0, stream>>>(x, bx, bh,
        planes,
        planes + (size_t)G4 * 256,
        planes + (size_t)2 * G4 * 256,
        planes + (size_t)3 * G4 * 256,
        out0, outh, outc, hbuf, ctrl);
}